// Round 14
// baseline (471.452 us; speedup 1.0000x reference)
//
#include <hip/hip_runtime.h>
#include <stdint.h>

// ---------------------------------------------------------------------------
// MultiHeadAttentionCrossWithWeights: B=8, Tq=448, Tk=1500, D=1280, H=20, Dh=64
// Round 14:
//  - attn: LDS 66KB -> 17KB (4-round qg-staged epilogue aliasing dead P);
//    loop identical to r13 (verified). 4 blocks/CU, 16 waves/CU.
//  - prep: single dispatch (vt | LDS-free kprep | cvt), heavy blocks first.
//  - gemm / weights unchanged (r13-verified).
// ---------------------------------------------------------------------------

typedef short bf16x8 __attribute__((ext_vector_type(8)));   // 8 bf16 in 4 VGPRs
typedef float f32x4  __attribute__((ext_vector_type(4)));

#define VMCNT(n) asm volatile("s_waitcnt vmcnt(" #n ")" ::: "memory")

__device__ __forceinline__ unsigned short f2bf(float f) {
  union { float f; unsigned int u; } c; c.f = f;
  unsigned int u = c.u;
  unsigned int r = (u + 0x7FFFu + ((u >> 16) & 1u)) >> 16;  // RNE
  return (unsigned short)r;
}

__device__ __forceinline__ float exp2_hw(float x) {
  float r;
  asm("v_exp_f32 %0, %1" : "=v"(r) : "v"(x));   // r = 2^x
  return r;
}

// async global->LDS, 16B per lane (GEMM staging only).
__device__ __forceinline__ void gld_lds16(const void* g, void* l) {
  __builtin_amdgcn_global_load_lds(
      (__attribute__((address_space(1))) void*)g,
      (__attribute__((address_space(3))) void*)l, 16, 0, 0);
}

__device__ __forceinline__ bf16x8 ldg16(const void* p) {
  return *reinterpret_cast<const bf16x8*>(p);
}

// ---------------------------------------------------------------------------
// Merged prep (one dispatch, 7680 blocks):
//   [0,1920):    v -> vfrag  (V^T MFMA-fragment 1KB chunks; LDS transpose)
//   [1920,3840): k -> kfrag  (K fragment chunks; LDS-free, coalesced)
//   [3840,7680): f32->bf16 cvt of Wq, Wo, x (contiguous dests)
__global__ __launch_bounds__(256) void prep_kernel(
    const float* __restrict__ x,  const float* __restrict__ Wq,
    const float* __restrict__ Wo, const float* __restrict__ k,
    const float* __restrict__ v,
    unsigned short* __restrict__ cvtdst,   // wqb | wob | xb contiguous
    unsigned short* __restrict__ kf,
    unsigned short* __restrict__ vf) {
  __shared__ __attribute__((aligned(16))) char T[128 * 132];
  int blk = blockIdx.x;
  const int t = threadIdx.x;

  if (blk < 1920) {
    // ---- vt: v (b,tk,1280) -> vfrag chunks
    //   chunk(bh,kc32,dg)[l*8+j] = V[kc*32+(l>>4)*8+j][h*64+dg*16+(l&15)]
    const int kt = blk % 12; blk /= 12;
    const int h = blk % 20; const int b = blk / 20;
    const size_t bh = b * 20 + h;

    const int c4 = t & 15;
    const int r  = t >> 4;
#pragma unroll
    for (int p = 0; p < 8; ++p) {
      const int kk = p * 16 + r;
      const int gtk = kt * 128 + kk;
      float4 a = {0.f, 0.f, 0.f, 0.f};
      if (gtk < 1500)
        a = *reinterpret_cast<const float4*>(v + (size_t)(b * 1500 + gtk) * 1280 + h * 64 + c4 * 4);
      unsigned int lo = f2bf(a.x) | ((unsigned int)f2bf(a.y) << 16);
      unsigned int hi = f2bf(a.z) | ((unsigned int)f2bf(a.w) << 16);
      char* base = T + kk * 132 + ((c4 ^ (kk & 15)) << 3);
      *reinterpret_cast<unsigned int*>(base)     = lo;
      *reinterpret_cast<unsigned int*>(base + 4) = hi;
    }
    __syncthreads();

    const int kc8 = t & 15;
    const int kc  = kt * 4 + (kc8 >> 2);
    const int l   = (t >> 4) | ((t & 3) << 4);
#pragma unroll
    for (int p = 0; p < 4; ++p) {
      const int d = p * 16 + (t >> 4);
      unsigned short r8[8];
#pragma unroll
      for (int j = 0; j < 8; ++j) {
        const int kk = kc8 * 8 + j;
        r8[j] = *reinterpret_cast<const unsigned short*>(
            T + kk * 132 + (((d >> 2) ^ (kk & 15)) << 3) + ((d & 3) << 1));
      }
      uint4 o;
      o.x = r8[0] | ((unsigned int)r8[1] << 16);
      o.y = r8[2] | ((unsigned int)r8[3] << 16);
      o.z = r8[4] | ((unsigned int)r8[5] << 16);
      o.w = r8[6] | ((unsigned int)r8[7] << 16);
      *reinterpret_cast<uint4*>(
          (char*)vf + (((bh * 48 + kc) * 4 + p) << 10) + l * 16) = o;
    }
    return;
  }

  if (blk < 3840) {
    // ---- kprep (LDS-free): chunk c = ((b*20+h)*96+kb)*2+h2
    //   chunk[l*8+j] = K[kb*16+(l&15)][h*64+h2*32+(l>>4)*8+j]
    const int w = t >> 6, l = t & 63;
    const int cbase = (blk - 1920) * 16 + w * 4;
#pragma unroll
    for (int i = 0; i < 4; ++i) {
      const int c = cbase + i;
      const int h2 = c & 1;
      const int kb = (c >> 1) % 96;
      const int rest = (c >> 1) / 96;
      const int h = rest % 20, b = rest / 20;
      const int row = kb * 16 + (l & 15);
      float4 a = {0.f, 0.f, 0.f, 0.f}, bq4 = {0.f, 0.f, 0.f, 0.f};
      if (row < 1500) {
        const float* src = k + (size_t)(b * 1500 + row) * 1280 + h * 64 + h2 * 32 + (l >> 4) * 8;
        a   = *reinterpret_cast<const float4*>(src);
        bq4 = *reinterpret_cast<const float4*>(src + 4);
      }
      uint4 o;
      o.x = f2bf(a.x)   | ((unsigned int)f2bf(a.y)   << 16);
      o.y = f2bf(a.z)   | ((unsigned int)f2bf(a.w)   << 16);
      o.z = f2bf(bq4.x) | ((unsigned int)f2bf(bq4.y) << 16);
      o.w = f2bf(bq4.z) | ((unsigned int)f2bf(bq4.w) << 16);
      *reinterpret_cast<uint4*>((char*)kf + ((size_t)c << 10) + l * 16) = o;
    }
    return;
  }

  // ---- cvt: Wq (204800 x8), Wo (204800 x8), x (573440 x8)
  {
    const int n0 = 204800, n1 = 204800;
    int i = (blk - 3840) * 256 + t;
    const float* src; int j = i;
    if (j < n0)               { src = Wq; }
    else if ((j -= n0) < n1)  { src = Wo; }
    else                      { j -= n1; src = x; }
    float4 a = *reinterpret_cast<const float4*>(src + (size_t)j * 8);
    float4 b = *reinterpret_cast<const float4*>(src + (size_t)j * 8 + 4);
    uint4 o;
    o.x = f2bf(a.x) | ((unsigned int)f2bf(a.y) << 16);
    o.y = f2bf(a.z) | ((unsigned int)f2bf(a.w) << 16);
    o.z = f2bf(b.x) | ((unsigned int)f2bf(b.y) << 16);
    o.w = f2bf(b.z) | ((unsigned int)f2bf(b.w) << 16);
    *reinterpret_cast<uint4*>(cvtdst + (size_t)i * 8) = o;
  }
}

// ---------------------------------------------------------------------------
// GEMM (bt form), 128x128 tile, BK=64, dbuf + counted vmcnt (verified).
template <int EPI>
__global__ __launch_bounds__(256) void gemm_bt(const unsigned short* __restrict__ A,
                                               const unsigned short* __restrict__ Bm,
                                               const float* __restrict__ bias,
                                               void* __restrict__ Cout,
                                               int M, int N, int K, float scale) {
  __shared__ __attribute__((aligned(16))) unsigned short As[2][128 * 64];
  __shared__ __attribute__((aligned(16))) unsigned short Bs[2][128 * 64];
  const int tid = threadIdx.x;
  const int w = tid >> 6, lane = tid & 63;
  const int l15 = lane & 15, l4 = lane >> 4;
  const int nBlk = N >> 7;
  const int cpx = gridDim.x >> 3;
  const int bid = (blockIdx.x & 7) * cpx + (blockIdx.x >> 3);
  const int bm = bid / nBlk, bn = bid % nBlk;
  const int m0 = bm << 7, n0 = bn << 7;
  const int wr = (w >> 1) << 6, wc = (w & 1) << 6;

  f32x4 acc[4][4] = {};

  auto stage = [&](int kt, int buf) {
    const int koff = kt << 6;
#pragma unroll
    for (int r = 0; r < 4; ++r) {
      const int base = (((w << 2) + r) << 10);
      const int p = base + (lane << 4);
      const int row = p >> 7;
      const int cbk = (p & 127) >> 1;
      gld_lds16(A  + ((size_t)(m0 + row) * K + koff + cbk), (char*)As[buf] + base);
      gld_lds16(Bm + ((size_t)(n0 + row) * K + koff + cbk), (char*)Bs[buf] + base);
    }
  };

  const int nKt = K >> 6;
  stage(0, 0);
  VMCNT(0);
  __builtin_amdgcn_s_barrier();

  for (int kt = 0; kt < nKt; ++kt) {
    const int buf = kt & 1;
    if (kt + 1 < nKt) {
      stage(kt + 1, buf ^ 1);
      VMCNT(8);
    } else {
      VMCNT(0);
    }
    __builtin_amdgcn_s_barrier();

    __builtin_amdgcn_s_setprio(1);
#pragma unroll
    for (int kk = 0; kk < 64; kk += 32) {
      bf16x8 af[4], bfr[4];
#pragma unroll
      for (int mi = 0; mi < 4; ++mi)
        af[mi] = *reinterpret_cast<const bf16x8*>(&As[buf][(wr + mi * 16 + l15) * 64 + kk + l4 * 8]);
#pragma unroll
      for (int ni = 0; ni < 4; ++ni)
        bfr[ni] = *reinterpret_cast<const bf16x8*>(&Bs[buf][(wc + ni * 16 + l15) * 64 + kk + l4 * 8]);
#pragma unroll
      for (int mi = 0; mi < 4; ++mi)
#pragma unroll
        for (int ni = 0; ni < 4; ++ni)
          acc[mi][ni] = __builtin_amdgcn_mfma_f32_16x16x32_bf16(af[mi], bfr[ni], acc[mi][ni], 0, 0, 0);
    }
    __builtin_amdgcn_s_setprio(0);
    __builtin_amdgcn_s_barrier();
  }

#pragma unroll
  for (int ni = 0; ni < 4; ++ni) {
    const int n = n0 + wc + ni * 16 + l15;
    const float bv = bias[n];
#pragma unroll
    for (int mi = 0; mi < 4; ++mi) {
#pragma unroll
      for (int i = 0; i < 4; ++i) {
        const int m = m0 + wr + mi * 16 + l4 * 4 + i;
        float vv = (acc[mi][ni][i] + bv) * scale;
        if (EPI == 0)
          ((unsigned short*)Cout)[(size_t)m * N + n] = f2bf(vv);
        else
          ((float*)Cout)[(size_t)m * N + n] = vv;
      }
    }
  }
}

// ---------------------------------------------------------------------------
// Flash attention: 64q k-split, direct frag-linear global K/V, register dbuf,
// no loop barriers (r13-verified loop). LDS 17KB: P/dump 16KB + Lb 1KB;
// epilogue staged over 4 qg-rounds. 4 blocks/CU.
__global__ __launch_bounds__(256, 4) void attn_kernel(const unsigned short* __restrict__ Qg,
                                                      const unsigned short* __restrict__ Kf,
                                                      const unsigned short* __restrict__ Vf,
                                                      unsigned short* __restrict__ Og,
                                                      float* __restrict__ ML) {
  __shared__ __attribute__((aligned(16))) char smem[17408];
  const int tid = threadIdx.x;
  const int w = tid >> 6, lane = tid & 63;
  const int l15 = lane & 15, l4 = lane >> 4;
  char* const Pw = smem + w * 4096;
  float* const Lb = reinterpret_cast<float*>(smem + 16384);

  int bid = (blockIdx.x & 7) * 140 + (blockIdx.x >> 3);
  const int qt = bid % 7; bid /= 7;
  const int h = bid % 20; const int b = bid / 20;
  const int tq0 = qt << 6;
  const int bh = b * 20 + h;

  bf16x8 qreg[4][2];
#pragma unroll
  for (int qg = 0; qg < 4; ++qg) {
    const unsigned short* qp =
        Qg + (size_t)(b * 448 + tq0 + qg * 16 + l15) * 1280 + h * 64 + l4 * 8;
    qreg[qg][0] = ldg16(qp);
    qreg[qg][1] = ldg16(qp + 32);
  }

  const char* const Kc = (const char*)Kf + ((size_t)bh * 192 << 10) + (w << 12) + (lane << 4);
  const char* const Vc = (const char*)Vf + ((size_t)bh * 192 << 10) + (w << 12) + (lane << 4);

  bf16x8 kf[2][2], bv[4];
#pragma unroll
  for (int kg = 0; kg < 2; ++kg)
#pragma unroll
    for (int h2 = 0; h2 < 2; ++h2)
      kf[kg][h2] = ldg16(Kc + kg * 2048 + h2 * 1024);
#pragma unroll
  for (int dg = 0; dg < 4; ++dg)
    bv[dg] = ldg16(Vc + dg * 1024);

  float l_p[4] = {0.f, 0.f, 0.f, 0.f};
  f32x4 o_acc[4][4] = {};

#pragma unroll 1
  for (int kt = 0; kt < 12; ++kt) {
    bf16x8 kfn[2][2], bvn[4];
    if (kt < 11) {
      const char* kp = Kc + (kt + 1) * 16384;
      const char* vp = Vc + (kt + 1) * 16384;
#pragma unroll
      for (int kg = 0; kg < 2; ++kg)
#pragma unroll
        for (int h2 = 0; h2 < 2; ++h2)
          kfn[kg][h2] = ldg16(kp + kg * 2048 + h2 * 1024);
#pragma unroll
      for (int dg = 0; dg < 4; ++dg)
        bvn[dg] = ldg16(vp + dg * 1024);
    }

    f32x4 s[2][4] = {};
    __builtin_amdgcn_s_setprio(1);
#pragma unroll
    for (int h2 = 0; h2 < 2; ++h2) {
#pragma unroll
      for (int qg = 0; qg < 4; ++qg)
        s[0][qg] = __builtin_amdgcn_mfma_f32_16x16x32_bf16(kf[0][h2], qreg[qg][h2], s[0][qg], 0, 0, 0);
#pragma unroll
      for (int qg = 0; qg < 4; ++qg)
        s[1][qg] = __builtin_amdgcn_mfma_f32_16x16x32_bf16(kf[1][h2], qreg[qg][h2], s[1][qg], 0, 0, 0);
    }
    __builtin_amdgcn_s_setprio(0);

    if (kt == 11) {   // mask local k >= 92 (1500 - 1408)
#pragma unroll
      for (int kg = 0; kg < 2; ++kg)
#pragma unroll
        for (int i = 0; i < 4; ++i)
          if ((w << 5) + (kg << 4) + (l4 << 2) + i >= 92) {
#pragma unroll
            for (int qg = 0; qg < 4; ++qg) s[kg][qg][i] = -1e30f;
          }
    }

#pragma unroll
    for (int kg = 0; kg < 2; ++kg)
#pragma unroll
      for (int qg = 0; qg < 4; ++qg) {
#pragma unroll
        for (int i = 0; i < 4; ++i) {
          float e = exp2_hw(fmaf(s[kg][qg][i], 1.44269504f, -17.31234049f));
          s[kg][qg][i] = e;
          l_p[qg] += e;
        }
        unsigned int u0, u1;
        asm("v_cvt_pk_bf16_f32 %0, %1, %2" : "=v"(u0) : "v"(s[kg][qg][0]), "v"(s[kg][qg][1]));
        asm("v_cvt_pk_bf16_f32 %0, %1, %2" : "=v"(u1) : "v"(s[kg][qg][2]), "v"(s[kg][qg][3]));
        unsigned long long u01 = ((unsigned long long)u1 << 32) | u0;
        *reinterpret_cast<unsigned long long*>(
            Pw + (qg << 10) + (((kg << 1) + (l4 >> 1)) << 8) + (l15 << 4) + ((l4 & 1) << 3)) = u01;
      }

    __builtin_amdgcn_s_setprio(1);
#pragma unroll
    for (int qg = 0; qg < 4; ++qg) {
      bf16x8 ap = *reinterpret_cast<const bf16x8*>(Pw + (qg << 10) + (lane << 4));
#pragma unroll
      for (int dg = 0; dg < 4; ++dg)
        o_acc[qg][dg] = __builtin_amdgcn_mfma_f32_16x16x32_bf16(ap, bv[dg], o_acc[qg][dg], 0, 0, 0);
    }
    __builtin_amdgcn_s_setprio(0);

#pragma unroll
    for (int kg = 0; kg < 2; ++kg)
#pragma unroll
      for (int h2 = 0; h2 < 2; ++h2)
        kf[kg][h2] = kfn[kg][h2];
#pragma unroll
    for (int dg = 0; dg < 4; ++dg)
      bv[dg] = bvn[dg];
  }

  // ---- l row-sums into Lb (wave-private slice; P region untouched)
#pragma unroll
  for (int qg = 0; qg < 4; ++qg) {
    float tsum = l_p[qg] + __shfl_xor(l_p[qg], 16);
    tsum += __shfl_xor(tsum, 32);
    if (l4 == 0) Lb[(w << 6) + (qg << 4) + l15] = tsum;
  }

  // ---- epilogue: 4 qg-rounds; dump aliases each wave's own dead P region
#pragma unroll
  for (int qg = 0; qg < 4; ++qg) {
#pragma unroll
    for (int dg = 0; dg < 4; ++dg)
      *reinterpret_cast<f32x4*>(Pw + (dg << 10) + (lane << 4)) = o_acc[qg][dg];
    __syncthreads();                      // dumps + (round 0) Lb visible

    f32x4 tsum = *reinterpret_cast<const f32x4*>(smem + (w << 10) + (lane << 4));
#pragma unroll
    for (int w2 = 1; w2 < 4; ++w2)
      tsum += *reinterpret_cast<const f32x4*>(smem + (w2 << 12) + (w << 10) + (lane << 4));
#pragma unroll
    for (int i = 0; i < 4; ++i) {
      const int q = (qg << 4) + (l4 << 2) + i;
      const float ltot = Lb[q] + Lb[64 + q] + Lb[128 + q] + Lb[192 + q];
      Og[(size_t)(b * 448 + tq0 + q) * 1280 + h * 64 + (w << 4) + l15] =
          f2bf(tsum[i] / ltot);
    }
    __syncthreads();                      // reads done before next round's dump
  }

  if (w == 0) {
    const float ltot = Lb[lane] + Lb[64 + lane] + Lb[128 + lane] + Lb[192 + lane];
    const size_t idx = (size_t)bh * 448 + tq0 + lane;
    ML[idx * 2]     = 12.0f;
    ML[idx * 2 + 1] = ltot;
  }
}

// ---------------------------------------------------------------------------
// Alignment weights: recompute QK for heads {4,7,11}, w = exp(s-m)/l (f32).
// Direct frag-linear K loads, prefetched, no LDS, no barriers (r13-verified).
__global__ __launch_bounds__(256) void weights_kernel(const unsigned short* __restrict__ Qg,
                                                      const unsigned short* __restrict__ Kf,
                                                      const float* __restrict__ ML,
                                                      float* __restrict__ Wout) {
  const int tid = threadIdx.x;
  const int w = tid >> 6, lane = tid & 63;
  const int l15 = lane & 15, l4 = lane >> 4;
  int bid = (blockIdx.x & 7) * 21 + (blockIdx.x >> 3);
  const int qt = bid % 7; bid /= 7;
  const int ha = bid % 3; const int b = bid / 3;
  const int h = (ha == 0) ? 4 : (ha == 1) ? 7 : 11;
  const int tq0 = qt << 6;

  const unsigned short* qptr =
      Qg + (size_t)(b * 448 + tq0 + w * 16 + l15) * 1280 + h * 64 + l4 * 8;
  bf16x8 qreg[2];
  qreg[0] = ldg16(qptr);
  qreg[1] = ldg16(qptr + 32);

  float m_r[4], rinv[4];
#pragma unroll
  for (int i = 0; i < 4; ++i) {
    size_t idx = (size_t)(b * 20 + h) * 448 + tq0 + w * 16 + l4 * 4 + i;
    m_r[i]  = ML[idx * 2];
    rinv[i] = 1.f / ML[idx * 2 + 1];
  }
  float* wbase = Wout + ((size_t)(b * 3 + ha) * 448 + tq0) * 1500;

  const char* const Kc = (const char*)Kf +
      ((size_t)(b * 20 + h) * 192 << 10) + (lane << 4);

  bf16x8 bk[4][2];
#pragma unroll
  for (int ni = 0; ni < 4; ++ni)
#pragma unroll
    for (int h2 = 0; h2 < 2; ++h2)
      bk[ni][h2] = ldg16(Kc + ((ni * 2 + h2) << 10));

#pragma unroll 1
  for (int kt = 0; kt < 24; ++kt) {
    bf16x8 bkn[4][2];
    if (kt < 23) {
      const char* kp = Kc + (size_t)(kt + 1) * 8192;
#pragma unroll
      for (int ni = 0; ni < 4; ++ni)
#pragma unroll
        for (int h2 = 0; h2 < 2; ++h2)
          bkn[ni][h2] = ldg16(kp + ((ni * 2 + h2) << 10));
    }

    f32x4 s[4] = {};
    __builtin_amdgcn_s_setprio(1);
#pragma unroll
    for (int h2 = 0; h2 < 2; ++h2)
#pragma unroll
      for (int ni = 0; ni < 4; ++ni)
        s[ni] = __builtin_amdgcn_mfma_f32_16x16x32_bf16(qreg[h2], bk[ni][h2], s[ni], 0, 0, 0);
    __builtin_amdgcn_s_setprio(0);

    const int k0 = kt << 6;
#pragma unroll
    for (int ni = 0; ni < 4; ++ni) {
      const int col = k0 + ni * 16 + l15;
      if (col < 1500) {
#pragma unroll
        for (int i = 0; i < 4; ++i) {
          const int row = w * 16 + l4 * 4 + i;
          wbase[(size_t)row * 1500 + col] = __expf(s[ni][i] - m_r[i]) * rinv[i];
        }
      }
    }

#pragma unroll
    for (int ni = 0; ni < 4; ++ni)
#pragma unroll
      for (int h2 = 0; h2 < 2; ++h2)
        bk[ni][h2] = bkn[ni][h2];
  }
}

// ---------------------------------------------------------------------------
extern "C" void kernel_launch(void* const* d_in, const int* in_sizes, int n_in,
                              void* d_out, int out_size, void* d_ws, size_t ws_size,
                              hipStream_t stream) {
  const float* x  = (const float*)d_in[0];
  const float* k  = (const float*)d_in[1];
  const float* v  = (const float*)d_in[2];
  const float* Wq = (const float*)d_in[3];
  const float* bq = (const float*)d_in[4];
  const float* Wo = (const float*)d_in[5];
  const float* bo = (const float*)d_in[6];
  float* out  = (float*)d_out;
  float* wout = out + (size_t)8 * 448 * 1280;

  char* ws = (char*)d_ws;
  unsigned short* wqb   = (unsigned short*)(ws);              //  3,276,800
  unsigned short* wob   = (unsigned short*)(ws + 3276800);    //  3,276,800
  unsigned short* xb    = (unsigned short*)(ws + 6553600);    //  9,175,040
  unsigned short* qs    = (unsigned short*)(ws + 15728640);   //  9,175,040
  unsigned short* kfrag = (unsigned short*)(ws + 24903680);   // 31,457,280
  unsigned short* vfrag = (unsigned short*)(ws + 56360960);   // 31,457,280
  float* ml             = (float*)(ws + 87818240);            //    573,440
  unsigned short* ao    = xb;   // xb dead after gemm1; attn output aliases it

  prep_kernel<<<7680, 256, 0, stream>>>(x, Wq, Wo, k, v, wqb, kfrag, vfrag);

  gemm_bt<0><<<280, 256, 0, stream>>>(xb, wqb, bq, (void*)qs, 3584, 1280, 1280, 0.125f);

  attn_kernel<<<8 * 20 * 7, 256, 0, stream>>>(qs, kfrag, vfrag, ao, ml);

  gemm_bt<1><<<280, 256, 0, stream>>>(ao, wob, bo, (void*)out, 3584, 1280, 1280, 1.0f);

  weights_kernel<<<8 * 3 * 7, 256, 0, stream>>>(qs, kfrag, ml, wout);
}

// Round 15
// 176.002 us; speedup vs baseline: 2.6787x; 2.6787x over previous
//
#include <hip/hip_runtime.h>
#include <stdint.h>

// ---------------------------------------------------------------------------
// MultiHeadAttentionCrossWithWeights: B=8, Tq=448, Tk=1500, D=1280, H=20, Dh=64
// Round 15: r14 with ONE fix — attn launch_bounds (256,4) -> (256,2).
//   (256,4) forced VGPR 108->64: accumulator+prefetch spill to scratch,
//   1.4GB HBM spill traffic, 382us. With (256,2) + 17.4KB LDS the HW gives
//   4 blocks/CU naturally (VGPR<=128 -> 4 waves/SIMD; LDS allows 9 blocks).
// Everything else identical to r14 (merged prep, staged epilogue, gemms).
// ---------------------------------------------------------------------------

typedef short bf16x8 __attribute__((ext_vector_type(8)));   // 8 bf16 in 4 VGPRs
typedef float f32x4  __attribute__((ext_vector_type(4)));

#define VMCNT(n) asm volatile("s_waitcnt vmcnt(" #n ")" ::: "memory")

__device__ __forceinline__ unsigned short f2bf(float f) {
  union { float f; unsigned int u; } c; c.f = f;
  unsigned int u = c.u;
  unsigned int r = (u + 0x7FFFu + ((u >> 16) & 1u)) >> 16;  // RNE
  return (unsigned short)r;
}

__device__ __forceinline__ float exp2_hw(float x) {
  float r;
  asm("v_exp_f32 %0, %1" : "=v"(r) : "v"(x));   // r = 2^x
  return r;
}

// async global->LDS, 16B per lane (GEMM staging only).
__device__ __forceinline__ void gld_lds16(const void* g, void* l) {
  __builtin_amdgcn_global_load_lds(
      (__attribute__((address_space(1))) void*)g,
      (__attribute__((address_space(3))) void*)l, 16, 0, 0);
}

__device__ __forceinline__ bf16x8 ldg16(const void* p) {
  return *reinterpret_cast<const bf16x8*>(p);
}

// ---------------------------------------------------------------------------
// Merged prep (one dispatch, 7680 blocks):
//   [0,1920):    v -> vfrag  (V^T MFMA-fragment 1KB chunks; LDS transpose)
//   [1920,3840): k -> kfrag  (K fragment chunks; LDS-free, coalesced)
//   [3840,7680): f32->bf16 cvt of Wq, Wo, x (contiguous dests)
__global__ __launch_bounds__(256) void prep_kernel(
    const float* __restrict__ x,  const float* __restrict__ Wq,
    const float* __restrict__ Wo, const float* __restrict__ k,
    const float* __restrict__ v,
    unsigned short* __restrict__ cvtdst,   // wqb | wob | xb contiguous
    unsigned short* __restrict__ kf,
    unsigned short* __restrict__ vf) {
  __shared__ __attribute__((aligned(16))) char T[128 * 132];
  int blk = blockIdx.x;
  const int t = threadIdx.x;

  if (blk < 1920) {
    // ---- vt: v (b,tk,1280) -> vfrag chunks
    const int kt = blk % 12; blk /= 12;
    const int h = blk % 20; const int b = blk / 20;
    const size_t bh = b * 20 + h;

    const int c4 = t & 15;
    const int r  = t >> 4;
#pragma unroll
    for (int p = 0; p < 8; ++p) {
      const int kk = p * 16 + r;
      const int gtk = kt * 128 + kk;
      float4 a = {0.f, 0.f, 0.f, 0.f};
      if (gtk < 1500)
        a = *reinterpret_cast<const float4*>(v + (size_t)(b * 1500 + gtk) * 1280 + h * 64 + c4 * 4);
      unsigned int lo = f2bf(a.x) | ((unsigned int)f2bf(a.y) << 16);
      unsigned int hi = f2bf(a.z) | ((unsigned int)f2bf(a.w) << 16);
      char* base = T + kk * 132 + ((c4 ^ (kk & 15)) << 3);
      *reinterpret_cast<unsigned int*>(base)     = lo;
      *reinterpret_cast<unsigned int*>(base + 4) = hi;
    }
    __syncthreads();

    const int kc8 = t & 15;
    const int kc  = kt * 4 + (kc8 >> 2);
    const int l   = (t >> 4) | ((t & 3) << 4);
#pragma unroll
    for (int p = 0; p < 4; ++p) {
      const int d = p * 16 + (t >> 4);
      unsigned short r8[8];
#pragma unroll
      for (int j = 0; j < 8; ++j) {
        const int kk = kc8 * 8 + j;
        r8[j] = *reinterpret_cast<const unsigned short*>(
            T + kk * 132 + (((d >> 2) ^ (kk & 15)) << 3) + ((d & 3) << 1));
      }
      uint4 o;
      o.x = r8[0] | ((unsigned int)r8[1] << 16);
      o.y = r8[2] | ((unsigned int)r8[3] << 16);
      o.z = r8[4] | ((unsigned int)r8[5] << 16);
      o.w = r8[6] | ((unsigned int)r8[7] << 16);
      *reinterpret_cast<uint4*>(
          (char*)vf + (((bh * 48 + kc) * 4 + p) << 10) + l * 16) = o;
    }
    return;
  }

  if (blk < 3840) {
    // ---- kprep (LDS-free): chunk c = ((b*20+h)*96+kb)*2+h2
    const int w = t >> 6, l = t & 63;
    const int cbase = (blk - 1920) * 16 + w * 4;
#pragma unroll
    for (int i = 0; i < 4; ++i) {
      const int c = cbase + i;
      const int h2 = c & 1;
      const int kb = (c >> 1) % 96;
      const int rest = (c >> 1) / 96;
      const int h = rest % 20, b = rest / 20;
      const int row = kb * 16 + (l & 15);
      float4 a = {0.f, 0.f, 0.f, 0.f}, bq4 = {0.f, 0.f, 0.f, 0.f};
      if (row < 1500) {
        const float* src = k + (size_t)(b * 1500 + row) * 1280 + h * 64 + h2 * 32 + (l >> 4) * 8;
        a   = *reinterpret_cast<const float4*>(src);
        bq4 = *reinterpret_cast<const float4*>(src + 4);
      }
      uint4 o;
      o.x = f2bf(a.x)   | ((unsigned int)f2bf(a.y)   << 16);
      o.y = f2bf(a.z)   | ((unsigned int)f2bf(a.w)   << 16);
      o.z = f2bf(bq4.x) | ((unsigned int)f2bf(bq4.y) << 16);
      o.w = f2bf(bq4.z) | ((unsigned int)f2bf(bq4.w) << 16);
      *reinterpret_cast<uint4*>((char*)kf + ((size_t)c << 10) + l * 16) = o;
    }
    return;
  }

  // ---- cvt: Wq (204800 x8), Wo (204800 x8), x (573440 x8)
  {
    const int n0 = 204800, n1 = 204800;
    int i = (blk - 3840) * 256 + t;
    const float* src; int j = i;
    if (j < n0)               { src = Wq; }
    else if ((j -= n0) < n1)  { src = Wo; }
    else                      { j -= n1; src = x; }
    float4 a = *reinterpret_cast<const float4*>(src + (size_t)j * 8);
    float4 b = *reinterpret_cast<const float4*>(src + (size_t)j * 8 + 4);
    uint4 o;
    o.x = f2bf(a.x) | ((unsigned int)f2bf(a.y) << 16);
    o.y = f2bf(a.z) | ((unsigned int)f2bf(a.w) << 16);
    o.z = f2bf(b.x) | ((unsigned int)f2bf(b.y) << 16);
    o.w = f2bf(b.z) | ((unsigned int)f2bf(b.w) << 16);
    *reinterpret_cast<uint4*>(cvtdst + (size_t)i * 8) = o;
  }
}

// ---------------------------------------------------------------------------
// GEMM (bt form), 128x128 tile, BK=64, dbuf + counted vmcnt (verified).
template <int EPI>
__global__ __launch_bounds__(256) void gemm_bt(const unsigned short* __restrict__ A,
                                               const unsigned short* __restrict__ Bm,
                                               const float* __restrict__ bias,
                                               void* __restrict__ Cout,
                                               int M, int N, int K, float scale) {
  __shared__ __attribute__((aligned(16))) unsigned short As[2][128 * 64];
  __shared__ __attribute__((aligned(16))) unsigned short Bs[2][128 * 64];
  const int tid = threadIdx.x;
  const int w = tid >> 6, lane = tid & 63;
  const int l15 = lane & 15, l4 = lane >> 4;
  const int nBlk = N >> 7;
  const int cpx = gridDim.x >> 3;
  const int bid = (blockIdx.x & 7) * cpx + (blockIdx.x >> 3);
  const int bm = bid / nBlk, bn = bid % nBlk;
  const int m0 = bm << 7, n0 = bn << 7;
  const int wr = (w >> 1) << 6, wc = (w & 1) << 6;

  f32x4 acc[4][4] = {};

  auto stage = [&](int kt, int buf) {
    const int koff = kt << 6;
#pragma unroll
    for (int r = 0; r < 4; ++r) {
      const int base = (((w << 2) + r) << 10);
      const int p = base + (lane << 4);
      const int row = p >> 7;
      const int cbk = (p & 127) >> 1;
      gld_lds16(A  + ((size_t)(m0 + row) * K + koff + cbk), (char*)As[buf] + base);
      gld_lds16(Bm + ((size_t)(n0 + row) * K + koff + cbk), (char*)Bs[buf] + base);
    }
  };

  const int nKt = K >> 6;
  stage(0, 0);
  VMCNT(0);
  __builtin_amdgcn_s_barrier();

  for (int kt = 0; kt < nKt; ++kt) {
    const int buf = kt & 1;
    if (kt + 1 < nKt) {
      stage(kt + 1, buf ^ 1);
      VMCNT(8);
    } else {
      VMCNT(0);
    }
    __builtin_amdgcn_s_barrier();

    __builtin_amdgcn_s_setprio(1);
#pragma unroll
    for (int kk = 0; kk < 64; kk += 32) {
      bf16x8 af[4], bfr[4];
#pragma unroll
      for (int mi = 0; mi < 4; ++mi)
        af[mi] = *reinterpret_cast<const bf16x8*>(&As[buf][(wr + mi * 16 + l15) * 64 + kk + l4 * 8]);
#pragma unroll
      for (int ni = 0; ni < 4; ++ni)
        bfr[ni] = *reinterpret_cast<const bf16x8*>(&Bs[buf][(wc + ni * 16 + l15) * 64 + kk + l4 * 8]);
#pragma unroll
      for (int mi = 0; mi < 4; ++mi)
#pragma unroll
        for (int ni = 0; ni < 4; ++ni)
          acc[mi][ni] = __builtin_amdgcn_mfma_f32_16x16x32_bf16(af[mi], bfr[ni], acc[mi][ni], 0, 0, 0);
    }
    __builtin_amdgcn_s_setprio(0);
    __builtin_amdgcn_s_barrier();
  }

#pragma unroll
  for (int ni = 0; ni < 4; ++ni) {
    const int n = n0 + wc + ni * 16 + l15;
    const float bv = bias[n];
#pragma unroll
    for (int mi = 0; mi < 4; ++mi) {
#pragma unroll
      for (int i = 0; i < 4; ++i) {
        const int m = m0 + wr + mi * 16 + l4 * 4 + i;
        float vv = (acc[mi][ni][i] + bv) * scale;
        if (EPI == 0)
          ((unsigned short*)Cout)[(size_t)m * N + n] = f2bf(vv);
        else
          ((float*)Cout)[(size_t)m * N + n] = vv;
      }
    }
  }
}

// ---------------------------------------------------------------------------
// Flash attention: 64q k-split, direct frag-linear global K/V, register dbuf,
// no loop barriers (r13-verified loop). LDS 17KB: P/dump 16KB + Lb 1KB;
// epilogue staged over 4 qg-rounds. launch_bounds(256,2): allocator free
// (~108 VGPR, no spill); HW occupancy = 4 blocks/CU via LDS+VGPR.
__global__ __launch_bounds__(256, 2) void attn_kernel(const unsigned short* __restrict__ Qg,
                                                      const unsigned short* __restrict__ Kf,
                                                      const unsigned short* __restrict__ Vf,
                                                      unsigned short* __restrict__ Og,
                                                      float* __restrict__ ML) {
  __shared__ __attribute__((aligned(16))) char smem[17408];
  const int tid = threadIdx.x;
  const int w = tid >> 6, lane = tid & 63;
  const int l15 = lane & 15, l4 = lane >> 4;
  char* const Pw = smem + w * 4096;
  float* const Lb = reinterpret_cast<float*>(smem + 16384);

  int bid = (blockIdx.x & 7) * 140 + (blockIdx.x >> 3);
  const int qt = bid % 7; bid /= 7;
  const int h = bid % 20; const int b = bid / 20;
  const int tq0 = qt << 6;
  const int bh = b * 20 + h;

  bf16x8 qreg[4][2];
#pragma unroll
  for (int qg = 0; qg < 4; ++qg) {
    const unsigned short* qp =
        Qg + (size_t)(b * 448 + tq0 + qg * 16 + l15) * 1280 + h * 64 + l4 * 8;
    qreg[qg][0] = ldg16(qp);
    qreg[qg][1] = ldg16(qp + 32);
  }

  const char* const Kc = (const char*)Kf + ((size_t)bh * 192 << 10) + (w << 12) + (lane << 4);
  const char* const Vc = (const char*)Vf + ((size_t)bh * 192 << 10) + (w << 12) + (lane << 4);

  bf16x8 kf[2][2], bv[4];
#pragma unroll
  for (int kg = 0; kg < 2; ++kg)
#pragma unroll
    for (int h2 = 0; h2 < 2; ++h2)
      kf[kg][h2] = ldg16(Kc + kg * 2048 + h2 * 1024);
#pragma unroll
  for (int dg = 0; dg < 4; ++dg)
    bv[dg] = ldg16(Vc + dg * 1024);

  float l_p[4] = {0.f, 0.f, 0.f, 0.f};
  f32x4 o_acc[4][4] = {};

#pragma unroll 1
  for (int kt = 0; kt < 12; ++kt) {
    bf16x8 kfn[2][2], bvn[4];
    if (kt < 11) {
      const char* kp = Kc + (kt + 1) * 16384;
      const char* vp = Vc + (kt + 1) * 16384;
#pragma unroll
      for (int kg = 0; kg < 2; ++kg)
#pragma unroll
        for (int h2 = 0; h2 < 2; ++h2)
          kfn[kg][h2] = ldg16(kp + kg * 2048 + h2 * 1024);
#pragma unroll
      for (int dg = 0; dg < 4; ++dg)
        bvn[dg] = ldg16(vp + dg * 1024);
    }

    f32x4 s[2][4] = {};
    __builtin_amdgcn_s_setprio(1);
#pragma unroll
    for (int h2 = 0; h2 < 2; ++h2) {
#pragma unroll
      for (int qg = 0; qg < 4; ++qg)
        s[0][qg] = __builtin_amdgcn_mfma_f32_16x16x32_bf16(kf[0][h2], qreg[qg][h2], s[0][qg], 0, 0, 0);
#pragma unroll
      for (int qg = 0; qg < 4; ++qg)
        s[1][qg] = __builtin_amdgcn_mfma_f32_16x16x32_bf16(kf[1][h2], qreg[qg][h2], s[1][qg], 0, 0, 0);
    }
    __builtin_amdgcn_s_setprio(0);

    if (kt == 11) {   // mask local k >= 92 (1500 - 1408)
#pragma unroll
      for (int kg = 0; kg < 2; ++kg)
#pragma unroll
        for (int i = 0; i < 4; ++i)
          if ((w << 5) + (kg << 4) + (l4 << 2) + i >= 92) {
#pragma unroll
            for (int qg = 0; qg < 4; ++qg) s[kg][qg][i] = -1e30f;
          }
    }

#pragma unroll
    for (int kg = 0; kg < 2; ++kg)
#pragma unroll
      for (int qg = 0; qg < 4; ++qg) {
#pragma unroll
        for (int i = 0; i < 4; ++i) {
          float e = exp2_hw(fmaf(s[kg][qg][i], 1.44269504f, -17.31234049f));
          s[kg][qg][i] = e;
          l_p[qg] += e;
        }
        unsigned int u0, u1;
        asm("v_cvt_pk_bf16_f32 %0, %1, %2" : "=v"(u0) : "v"(s[kg][qg][0]), "v"(s[kg][qg][1]));
        asm("v_cvt_pk_bf16_f32 %0, %1, %2" : "=v"(u1) : "v"(s[kg][qg][2]), "v"(s[kg][qg][3]));
        unsigned long long u01 = ((unsigned long long)u1 << 32) | u0;
        *reinterpret_cast<unsigned long long*>(
            Pw + (qg << 10) + (((kg << 1) + (l4 >> 1)) << 8) + (l15 << 4) + ((l4 & 1) << 3)) = u01;
      }

    __builtin_amdgcn_s_setprio(1);
#pragma unroll
    for (int qg = 0; qg < 4; ++qg) {
      bf16x8 ap = *reinterpret_cast<const bf16x8*>(Pw + (qg << 10) + (lane << 4));
#pragma unroll
      for (int dg = 0; dg < 4; ++dg)
        o_acc[qg][dg] = __builtin_amdgcn_mfma_f32_16x16x32_bf16(ap, bv[dg], o_acc[qg][dg], 0, 0, 0);
    }
    __builtin_amdgcn_s_setprio(0);

#pragma unroll
    for (int kg = 0; kg < 2; ++kg)
#pragma unroll
      for (int h2 = 0; h2 < 2; ++h2)
        kf[kg][h2] = kfn[kg][h2];
#pragma unroll
    for (int dg = 0; dg < 4; ++dg)
      bv[dg] = bvn[dg];
  }

  // ---- l row-sums into Lb (wave-private slice; P region untouched)
#pragma unroll
  for (int qg = 0; qg < 4; ++qg) {
    float tsum = l_p[qg] + __shfl_xor(l_p[qg], 16);
    tsum += __shfl_xor(tsum, 32);
    if (l4 == 0) Lb[(w << 6) + (qg << 4) + l15] = tsum;
  }

  // ---- epilogue: 4 qg-rounds; dump aliases each wave's own dead P region
#pragma unroll
  for (int qg = 0; qg < 4; ++qg) {
#pragma unroll
    for (int dg = 0; dg < 4; ++dg)
      *reinterpret_cast<f32x4*>(Pw + (dg << 10) + (lane << 4)) = o_acc[qg][dg];
    __syncthreads();                      // dumps + (round 0) Lb visible

    f32x4 tsum = *reinterpret_cast<const f32x4*>(smem + (w << 10) + (lane << 4));
#pragma unroll
    for (int w2 = 1; w2 < 4; ++w2)
      tsum += *reinterpret_cast<const f32x4*>(smem + (w2 << 12) + (w << 10) + (lane << 4));
#pragma unroll
    for (int i = 0; i < 4; ++i) {
      const int q = (qg << 4) + (l4 << 2) + i;
      const float ltot = Lb[q] + Lb[64 + q] + Lb[128 + q] + Lb[192 + q];
      Og[(size_t)(b * 448 + tq0 + q) * 1280 + h * 64 + (w << 4) + l15] =
          f2bf(tsum[i] / ltot);
    }
    __syncthreads();                      // reads done before next round's dump
  }

  if (w == 0) {
    const float ltot = Lb[lane] + Lb[64 + lane] + Lb[128 + lane] + Lb[192 + lane];
    const size_t idx = (size_t)bh * 448 + tq0 + lane;
    ML[idx * 2]     = 12.0f;
    ML[idx * 2 + 1] = ltot;
  }
}

// ---------------------------------------------------------------------------
// Alignment weights: recompute QK for heads {4,7,11}, w = exp(s-m)/l (f32).
// Direct frag-linear K loads, prefetched, no LDS, no barriers (r13-verified).
__global__ __launch_bounds__(256) void weights_kernel(const unsigned short* __restrict__ Qg,
                                                      const unsigned short* __restrict__ Kf,
                                                      const float* __restrict__ ML,
                                                      float* __restrict__ Wout) {
  const int tid = threadIdx.x;
  const int w = tid >> 6, lane = tid & 63;
  const int l15 = lane & 15, l4 = lane >> 4;
  int bid = (blockIdx.x & 7) * 21 + (blockIdx.x >> 3);
  const int qt = bid % 7; bid /= 7;
  const int ha = bid % 3; const int b = bid / 3;
  const int h = (ha == 0) ? 4 : (ha == 1) ? 7 : 11;
  const int tq0 = qt << 6;

  const unsigned short* qptr =
      Qg + (size_t)(b * 448 + tq0 + w * 16 + l15) * 1280 + h * 64 + l4 * 8;
  bf16x8 qreg[2];
  qreg[0] = ldg16(qptr);
  qreg[1] = ldg16(qptr + 32);

  float m_r[4], rinv[4];
#pragma unroll
  for (int i = 0; i < 4; ++i) {
    size_t idx = (size_t)(b * 20 + h) * 448 + tq0 + w * 16 + l4 * 4 + i;
    m_r[i]  = ML[idx * 2];
    rinv[i] = 1.f / ML[idx * 2 + 1];
  }
  float* wbase = Wout + ((size_t)(b * 3 + ha) * 448 + tq0) * 1500;

  const char* const Kc = (const char*)Kf +
      ((size_t)(b * 20 + h) * 192 << 10) + (lane << 4);

  bf16x8 bk[4][2];
#pragma unroll
  for (int ni = 0; ni < 4; ++ni)
#pragma unroll
    for (int h2 = 0; h2 < 2; ++h2)
      bk[ni][h2] = ldg16(Kc + ((ni * 2 + h2) << 10));

#pragma unroll 1
  for (int kt = 0; kt < 24; ++kt) {
    bf16x8 bkn[4][2];
    if (kt < 23) {
      const char* kp = Kc + (size_t)(kt + 1) * 8192;
#pragma unroll
      for (int ni = 0; ni < 4; ++ni)
#pragma unroll
        for (int h2 = 0; h2 < 2; ++h2)
          bkn[ni][h2] = ldg16(kp + ((ni * 2 + h2) << 10));
    }

    f32x4 s[4] = {};
    __builtin_amdgcn_s_setprio(1);
#pragma unroll
    for (int h2 = 0; h2 < 2; ++h2)
#pragma unroll
      for (int ni = 0; ni < 4; ++ni)
        s[ni] = __builtin_amdgcn_mfma_f32_16x16x32_bf16(qreg[h2], bk[ni][h2], s[ni], 0, 0, 0);
    __builtin_amdgcn_s_setprio(0);

    const int k0 = kt << 6;
#pragma unroll
    for (int ni = 0; ni < 4; ++ni) {
      const int col = k0 + ni * 16 + l15;
      if (col < 1500) {
#pragma unroll
        for (int i = 0; i < 4; ++i) {
          const int row = w * 16 + l4 * 4 + i;
          wbase[(size_t)row * 1500 + col] = __expf(s[ni][i] - m_r[i]) * rinv[i];
        }
      }
    }

#pragma unroll
    for (int ni = 0; ni < 4; ++ni)
#pragma unroll
      for (int h2 = 0; h2 < 2; ++h2)
        bk[ni][h2] = bkn[ni][h2];
  }
}

// ---------------------------------------------------------------------------
extern "C" void kernel_launch(void* const* d_in, const int* in_sizes, int n_in,
                              void* d_out, int out_size, void* d_ws, size_t ws_size,
                              hipStream_t stream) {
  const float* x  = (const float*)d_in[0];
  const float* k  = (const float*)d_in[1];
  const float* v  = (const float*)d_in[2];
  const float* Wq = (const float*)d_in[3];
  const float* bq = (const float*)d_in[4];
  const float* Wo = (const float*)d_in[5];
  const float* bo = (const float*)d_in[6];
  float* out  = (float*)d_out;
  float* wout = out + (size_t)8 * 448 * 1280;

  char* ws = (char*)d_ws;
  unsigned short* wqb   = (unsigned short*)(ws);              //  3,276,800
  unsigned short* wob   = (unsigned short*)(ws + 3276800);    //  3,276,800
  unsigned short* xb    = (unsigned short*)(ws + 6553600);    //  9,175,040
  unsigned short* qs    = (unsigned short*)(ws + 15728640);   //  9,175,040
  unsigned short* kfrag = (unsigned short*)(ws + 24903680);   // 31,457,280
  unsigned short* vfrag = (unsigned short*)(ws + 56360960);   // 31,457,280
  float* ml             = (float*)(ws + 87818240);            //    573,440
  unsigned short* ao    = xb;   // xb dead after gemm1; attn output aliases it

  prep_kernel<<<7680, 256, 0, stream>>>(x, Wq, Wo, k, v, wqb, kfrag, vfrag);

  gemm_bt<0><<<280, 256, 0, stream>>>(xb, wqb, bq, (void*)qs, 3584, 1280, 1280, 0.125f);

  attn_kernel<<<8 * 20 * 7, 256, 0, stream>>>(qs, kfrag, vfrag, ao, ml);

  gemm_bt<1><<<280, 256, 0, stream>>>(ao, wob, bo, (void*)out, 3584, 1280, 1280, 1.0f);

  weights_kernel<<<8 * 3 * 7, 256, 0, stream>>>(qs, kfrag, ml, wout);
}

// Round 16
// 174.239 us; speedup vs baseline: 2.7058x; 1.0101x over previous
//
#include <hip/hip_runtime.h>
#include <stdint.h>

// ---------------------------------------------------------------------------
// MultiHeadAttentionCrossWithWeights: B=8, Tq=448, Tk=1500, D=1280, H=20, Dh=64
// Round 16:
//  - prep: vt branch rewritten as direct-global gather (no LDS, no barriers,
//    coalesced 1KB chunk stores). kprep/cvt unchanged. prep now LDS-free.
//  - gemm: BM 128 -> 64 (560 blocks, 2.19/CU; LDS 48KB -> 3 blocks/CU) to fix
//    the 1-wave/SIMD latency exposure. Same dbuf + counted vmcnt structure.
//  - attn / weights identical to r15 (verified, no spill, 4 blocks/CU).
// ---------------------------------------------------------------------------

typedef short bf16x8 __attribute__((ext_vector_type(8)));   // 8 bf16 in 4 VGPRs
typedef float f32x4  __attribute__((ext_vector_type(4)));

#define VMCNT(n) asm volatile("s_waitcnt vmcnt(" #n ")" ::: "memory")

__device__ __forceinline__ unsigned short f2bf(float f) {
  union { float f; unsigned int u; } c; c.f = f;
  unsigned int u = c.u;
  unsigned int r = (u + 0x7FFFu + ((u >> 16) & 1u)) >> 16;  // RNE
  return (unsigned short)r;
}

__device__ __forceinline__ float exp2_hw(float x) {
  float r;
  asm("v_exp_f32 %0, %1" : "=v"(r) : "v"(x));   // r = 2^x
  return r;
}

// async global->LDS, 16B per lane (GEMM staging only).
__device__ __forceinline__ void gld_lds16(const void* g, void* l) {
  __builtin_amdgcn_global_load_lds(
      (__attribute__((address_space(1))) void*)g,
      (__attribute__((address_space(3))) void*)l, 16, 0, 0);
}

__device__ __forceinline__ bf16x8 ldg16(const void* p) {
  return *reinterpret_cast<const bf16x8*>(p);
}

__device__ __forceinline__ unsigned int pkbf(float a, float b) {
  unsigned int u;
  asm("v_cvt_pk_bf16_f32 %0, %1, %2" : "=v"(u) : "v"(a), "v"(b));
  return u;
}

// ---------------------------------------------------------------------------
// Merged prep (one dispatch, 7680 blocks, LDS-free):
//   [0,1920):    v -> vfrag  (direct-global gather, coalesced 1KB chunk stores)
//   [1920,3840): k -> kfrag  (K fragment chunks; coalesced)
//   [3840,7680): f32->bf16 cvt of Wq, Wo, x (contiguous dests)
__global__ __launch_bounds__(256) void prep_kernel(
    const float* __restrict__ x,  const float* __restrict__ Wq,
    const float* __restrict__ Wo, const float* __restrict__ k,
    const float* __restrict__ v,
    unsigned short* __restrict__ cvtdst,   // wqb | wob | xb contiguous
    unsigned short* __restrict__ kf,
    unsigned short* __restrict__ vf) {
  int blk = blockIdx.x;
  const int t = threadIdx.x;

  if (blk < 1920) {
    // ---- vt (gather): chunk(bh,kc32,dg)[l*8+j] = V[kc*32+(l>>4)*8+j][h*64+dg*16+(l&15)]
    const int kt = blk % 12; blk /= 12;
    const int h = blk % 20; const int b = blk / 20;
    const size_t bh = b * 20 + h;
    const int w = t >> 6, l = t & 63;
    const int kc = kt * 4 + w;              // this wave's 32-k block
    const int r0 = kc * 32 + ((l >> 4) << 3);
    const int col0 = h * 64 + (l & 15);

#pragma unroll
    for (int dg = 0; dg < 4; ++dg) {
      float val[8];
#pragma unroll
      for (int j = 0; j < 8; ++j) {
        const int row = r0 + j;
        val[j] = (row < 1500)
            ? v[(size_t)(b * 1500 + row) * 1280 + col0 + dg * 16] : 0.f;
      }
      uint4 o;
      o.x = pkbf(val[0], val[1]);
      o.y = pkbf(val[2], val[3]);
      o.z = pkbf(val[4], val[5]);
      o.w = pkbf(val[6], val[7]);
      *reinterpret_cast<uint4*>(
          (char*)vf + ((((bh * 48 + kc) << 2) + dg) << 10) + l * 16) = o;
    }
    return;
  }

  if (blk < 3840) {
    // ---- kprep: chunk c = ((b*20+h)*96+kb)*2+h2
    //   chunk[l*8+j] = K[kb*16+(l&15)][h*64+h2*32+(l>>4)*8+j]
    const int w = t >> 6, l = t & 63;
    const int cbase = (blk - 1920) * 16 + w * 4;
#pragma unroll
    for (int i = 0; i < 4; ++i) {
      const int c = cbase + i;
      const int h2 = c & 1;
      const int kb = (c >> 1) % 96;
      const int rest = (c >> 1) / 96;
      const int h = rest % 20, b = rest / 20;
      const int row = kb * 16 + (l & 15);
      float4 a = {0.f, 0.f, 0.f, 0.f}, bq4 = {0.f, 0.f, 0.f, 0.f};
      if (row < 1500) {
        const float* src = k + (size_t)(b * 1500 + row) * 1280 + h * 64 + h2 * 32 + (l >> 4) * 8;
        a   = *reinterpret_cast<const float4*>(src);
        bq4 = *reinterpret_cast<const float4*>(src + 4);
      }
      uint4 o;
      o.x = f2bf(a.x)   | ((unsigned int)f2bf(a.y)   << 16);
      o.y = f2bf(a.z)   | ((unsigned int)f2bf(a.w)   << 16);
      o.z = f2bf(bq4.x) | ((unsigned int)f2bf(bq4.y) << 16);
      o.w = f2bf(bq4.z) | ((unsigned int)f2bf(bq4.w) << 16);
      *reinterpret_cast<uint4*>((char*)kf + ((size_t)c << 10) + l * 16) = o;
    }
    return;
  }

  // ---- cvt: Wq (204800 x8), Wo (204800 x8), x (573440 x8)
  {
    const int n0 = 204800, n1 = 204800;
    int i = (blk - 3840) * 256 + t;
    const float* src; int j = i;
    if (j < n0)               { src = Wq; }
    else if ((j -= n0) < n1)  { src = Wo; }
    else                      { j -= n1; src = x; }
    float4 a = *reinterpret_cast<const float4*>(src + (size_t)j * 8);
    float4 b = *reinterpret_cast<const float4*>(src + (size_t)j * 8 + 4);
    uint4 o;
    o.x = f2bf(a.x) | ((unsigned int)f2bf(a.y) << 16);
    o.y = f2bf(a.z) | ((unsigned int)f2bf(a.w) << 16);
    o.z = f2bf(b.x) | ((unsigned int)f2bf(b.y) << 16);
    o.w = f2bf(b.z) | ((unsigned int)f2bf(b.w) << 16);
    *reinterpret_cast<uint4*>(cvtdst + (size_t)i * 8) = o;
  }
}

// ---------------------------------------------------------------------------
// GEMM (bt form): C[m][n] = sum_k A[m,k]*B[n,k]; epi 0: bf16 (C+bias)*scale, 1: f32
// 64x128 tile, BK=64, 4 waves (2x2: 32x64 each), dbuf + counted vmcnt(6).
// 560 blocks -> 2.19/CU, LDS 48KB -> 3 blocks/CU (fixes 1-wave/SIMD exposure).
template <int EPI>
__global__ __launch_bounds__(256) void gemm_bt(const unsigned short* __restrict__ A,
                                               const unsigned short* __restrict__ Bm,
                                               const float* __restrict__ bias,
                                               void* __restrict__ Cout,
                                               int M, int N, int K, float scale) {
  __shared__ __attribute__((aligned(16))) unsigned short As[2][64 * 64];
  __shared__ __attribute__((aligned(16))) unsigned short Bs[2][128 * 64];
  const int tid = threadIdx.x;
  const int w = tid >> 6, lane = tid & 63;
  const int l15 = lane & 15, l4 = lane >> 4;
  const int nBlk = N >> 7;                        // 128-col tiles
  const int cpx = gridDim.x >> 3;
  const int bid = (blockIdx.x & 7) * cpx + (blockIdx.x >> 3);
  const int bm = bid / nBlk, bn = bid % nBlk;
  const int m0 = bm << 6, n0 = bn << 7;
  const int wr = (w >> 1) << 5, wc = (w & 1) << 6;

  f32x4 acc[2][4] = {};

  auto stage = [&](int kt, int buf) {
    const int koff = kt << 6;
#pragma unroll
    for (int r = 0; r < 2; ++r) {                 // A: 8 chunks of 1KB
      const int base = ((w * 2 + r) << 10);
      const int p = base + (lane << 4);
      const int row = p >> 7;
      const int cbk = (p & 127) >> 1;
      gld_lds16(A + ((size_t)(m0 + row) * K + koff + cbk), (char*)As[buf] + base);
    }
#pragma unroll
    for (int r = 0; r < 4; ++r) {                 // B: 16 chunks of 1KB
      const int base = ((w * 4 + r) << 10);
      const int p = base + (lane << 4);
      const int row = p >> 7;
      const int cbk = (p & 127) >> 1;
      gld_lds16(Bm + ((size_t)(n0 + row) * K + koff + cbk), (char*)Bs[buf] + base);
    }
  };

  const int nKt = K >> 6;
  stage(0, 0);
  VMCNT(0);
  __builtin_amdgcn_s_barrier();

  for (int kt = 0; kt < nKt; ++kt) {
    const int buf = kt & 1;
    if (kt + 1 < nKt) {
      stage(kt + 1, buf ^ 1);
      VMCNT(6);                  // prev tile's 6 DMAs/thread landed; 6 in flight
    } else {
      VMCNT(0);
    }
    __builtin_amdgcn_s_barrier();

    __builtin_amdgcn_s_setprio(1);
#pragma unroll
    for (int kk = 0; kk < 64; kk += 32) {
      bf16x8 af[2], bfr[4];
#pragma unroll
      for (int mi = 0; mi < 2; ++mi)
        af[mi] = *reinterpret_cast<const bf16x8*>(&As[buf][(wr + mi * 16 + l15) * 64 + kk + l4 * 8]);
#pragma unroll
      for (int ni = 0; ni < 4; ++ni)
        bfr[ni] = *reinterpret_cast<const bf16x8*>(&Bs[buf][(wc + ni * 16 + l15) * 64 + kk + l4 * 8]);
#pragma unroll
      for (int mi = 0; mi < 2; ++mi)
#pragma unroll
        for (int ni = 0; ni < 4; ++ni)
          acc[mi][ni] = __builtin_amdgcn_mfma_f32_16x16x32_bf16(af[mi], bfr[ni], acc[mi][ni], 0, 0, 0);
    }
    __builtin_amdgcn_s_setprio(0);
    __builtin_amdgcn_s_barrier();
  }

#pragma unroll
  for (int ni = 0; ni < 4; ++ni) {
    const int n = n0 + wc + ni * 16 + l15;
    const float bv = bias[n];
#pragma unroll
    for (int mi = 0; mi < 2; ++mi) {
#pragma unroll
      for (int i = 0; i < 4; ++i) {
        const int m = m0 + wr + mi * 16 + l4 * 4 + i;
        float vv = (acc[mi][ni][i] + bv) * scale;
        if (EPI == 0)
          ((unsigned short*)Cout)[(size_t)m * N + n] = f2bf(vv);
        else
          ((float*)Cout)[(size_t)m * N + n] = vv;
      }
    }
  }
}

// ---------------------------------------------------------------------------
// Flash attention: 64q k-split, direct frag-linear global K/V, register dbuf,
// no loop barriers. LDS 17KB; staged epilogue. (r15-verified, unchanged)
__global__ __launch_bounds__(256, 2) void attn_kernel(const unsigned short* __restrict__ Qg,
                                                      const unsigned short* __restrict__ Kf,
                                                      const unsigned short* __restrict__ Vf,
                                                      unsigned short* __restrict__ Og,
                                                      float* __restrict__ ML) {
  __shared__ __attribute__((aligned(16))) char smem[17408];
  const int tid = threadIdx.x;
  const int w = tid >> 6, lane = tid & 63;
  const int l15 = lane & 15, l4 = lane >> 4;
  char* const Pw = smem + w * 4096;
  float* const Lb = reinterpret_cast<float*>(smem + 16384);

  int bid = (blockIdx.x & 7) * 140 + (blockIdx.x >> 3);
  const int qt = bid % 7; bid /= 7;
  const int h = bid % 20; const int b = bid / 20;
  const int tq0 = qt << 6;
  const int bh = b * 20 + h;

  bf16x8 qreg[4][2];
#pragma unroll
  for (int qg = 0; qg < 4; ++qg) {
    const unsigned short* qp =
        Qg + (size_t)(b * 448 + tq0 + qg * 16 + l15) * 1280 + h * 64 + l4 * 8;
    qreg[qg][0] = ldg16(qp);
    qreg[qg][1] = ldg16(qp + 32);
  }

  const char* const Kc = (const char*)Kf + ((size_t)bh * 192 << 10) + (w << 12) + (lane << 4);
  const char* const Vc = (const char*)Vf + ((size_t)bh * 192 << 10) + (w << 12) + (lane << 4);

  bf16x8 kf[2][2], bv[4];
#pragma unroll
  for (int kg = 0; kg < 2; ++kg)
#pragma unroll
    for (int h2 = 0; h2 < 2; ++h2)
      kf[kg][h2] = ldg16(Kc + kg * 2048 + h2 * 1024);
#pragma unroll
  for (int dg = 0; dg < 4; ++dg)
    bv[dg] = ldg16(Vc + dg * 1024);

  float l_p[4] = {0.f, 0.f, 0.f, 0.f};
  f32x4 o_acc[4][4] = {};

#pragma unroll 1
  for (int kt = 0; kt < 12; ++kt) {
    bf16x8 kfn[2][2], bvn[4];
    if (kt < 11) {
      const char* kp = Kc + (kt + 1) * 16384;
      const char* vp = Vc + (kt + 1) * 16384;
#pragma unroll
      for (int kg = 0; kg < 2; ++kg)
#pragma unroll
        for (int h2 = 0; h2 < 2; ++h2)
          kfn[kg][h2] = ldg16(kp + kg * 2048 + h2 * 1024);
#pragma unroll
      for (int dg = 0; dg < 4; ++dg)
        bvn[dg] = ldg16(vp + dg * 1024);
    }

    f32x4 s[2][4] = {};
    __builtin_amdgcn_s_setprio(1);
#pragma unroll
    for (int h2 = 0; h2 < 2; ++h2) {
#pragma unroll
      for (int qg = 0; qg < 4; ++qg)
        s[0][qg] = __builtin_amdgcn_mfma_f32_16x16x32_bf16(kf[0][h2], qreg[qg][h2], s[0][qg], 0, 0, 0);
#pragma unroll
      for (int qg = 0; qg < 4; ++qg)
        s[1][qg] = __builtin_amdgcn_mfma_f32_16x16x32_bf16(kf[1][h2], qreg[qg][h2], s[1][qg], 0, 0, 0);
    }
    __builtin_amdgcn_s_setprio(0);

    if (kt == 11) {   // mask local k >= 92 (1500 - 1408)
#pragma unroll
      for (int kg = 0; kg < 2; ++kg)
#pragma unroll
        for (int i = 0; i < 4; ++i)
          if ((w << 5) + (kg << 4) + (l4 << 2) + i >= 92) {
#pragma unroll
            for (int qg = 0; qg < 4; ++qg) s[kg][qg][i] = -1e30f;
          }
    }

#pragma unroll
    for (int kg = 0; kg < 2; ++kg)
#pragma unroll
      for (int qg = 0; qg < 4; ++qg) {
#pragma unroll
        for (int i = 0; i < 4; ++i) {
          float e = exp2_hw(fmaf(s[kg][qg][i], 1.44269504f, -17.31234049f));
          s[kg][qg][i] = e;
          l_p[qg] += e;
        }
        unsigned int u0 = pkbf(s[kg][qg][0], s[kg][qg][1]);
        unsigned int u1 = pkbf(s[kg][qg][2], s[kg][qg][3]);
        unsigned long long u01 = ((unsigned long long)u1 << 32) | u0;
        *reinterpret_cast<unsigned long long*>(
            Pw + (qg << 10) + (((kg << 1) + (l4 >> 1)) << 8) + (l15 << 4) + ((l4 & 1) << 3)) = u01;
      }

    __builtin_amdgcn_s_setprio(1);
#pragma unroll
    for (int qg = 0; qg < 4; ++qg) {
      bf16x8 ap = *reinterpret_cast<const bf16x8*>(Pw + (qg << 10) + (lane << 4));
#pragma unroll
      for (int dg = 0; dg < 4; ++dg)
        o_acc[qg][dg] = __builtin_amdgcn_mfma_f32_16x16x32_bf16(ap, bv[dg], o_acc[qg][dg], 0, 0, 0);
    }
    __builtin_amdgcn_s_setprio(0);

#pragma unroll
    for (int kg = 0; kg < 2; ++kg)
#pragma unroll
      for (int h2 = 0; h2 < 2; ++h2)
        kf[kg][h2] = kfn[kg][h2];
#pragma unroll
    for (int dg = 0; dg < 4; ++dg)
      bv[dg] = bvn[dg];
  }

  // ---- l row-sums into Lb (wave-private slice; P region untouched)
#pragma unroll
  for (int qg = 0; qg < 4; ++qg) {
    float tsum = l_p[qg] + __shfl_xor(l_p[qg], 16);
    tsum += __shfl_xor(tsum, 32);
    if (l4 == 0) Lb[(w << 6) + (qg << 4) + l15] = tsum;
  }

  // ---- epilogue: 4 qg-rounds; dump aliases each wave's own dead P region
#pragma unroll
  for (int qg = 0; qg < 4; ++qg) {
#pragma unroll
    for (int dg = 0; dg < 4; ++dg)
      *reinterpret_cast<f32x4*>(Pw + (dg << 10) + (lane << 4)) = o_acc[qg][dg];
    __syncthreads();

    f32x4 tsum = *reinterpret_cast<const f32x4*>(smem + (w << 10) + (lane << 4));
#pragma unroll
    for (int w2 = 1; w2 < 4; ++w2)
      tsum += *reinterpret_cast<const f32x4*>(smem + (w2 << 12) + (w << 10) + (lane << 4));
#pragma unroll
    for (int i = 0; i < 4; ++i) {
      const int q = (qg << 4) + (l4 << 2) + i;
      const float ltot = Lb[q] + Lb[64 + q] + Lb[128 + q] + Lb[192 + q];
      Og[(size_t)(b * 448 + tq0 + q) * 1280 + h * 64 + (w << 4) + l15] =
          f2bf(tsum[i] / ltot);
    }
    __syncthreads();
  }

  if (w == 0) {
    const float ltot = Lb[lane] + Lb[64 + lane] + Lb[128 + lane] + Lb[192 + lane];
    const size_t idx = (size_t)bh * 448 + tq0 + lane;
    ML[idx * 2]     = 12.0f;
    ML[idx * 2 + 1] = ltot;
  }
}

// ---------------------------------------------------------------------------
// Alignment weights: recompute QK for heads {4,7,11}, w = exp(s-m)/l (f32).
// Direct frag-linear K loads, prefetched, no LDS, no barriers (verified).
__global__ __launch_bounds__(256) void weights_kernel(const unsigned short* __restrict__ Qg,
                                                      const unsigned short* __restrict__ Kf,
                                                      const float* __restrict__ ML,
                                                      float* __restrict__ Wout) {
  const int tid = threadIdx.x;
  const int w = tid >> 6, lane = tid & 63;
  const int l15 = lane & 15, l4 = lane >> 4;
  int bid = (blockIdx.x & 7) * 21 + (blockIdx.x >> 3);
  const int qt = bid % 7; bid /= 7;
  const int ha = bid % 3; const int b = bid / 3;
  const int h = (ha == 0) ? 4 : (ha == 1) ? 7 : 11;
  const int tq0 = qt << 6;

  const unsigned short* qptr =
      Qg + (size_t)(b * 448 + tq0 + w * 16 + l15) * 1280 + h * 64 + l4 * 8;
  bf16x8 qreg[2];
  qreg[0] = ldg16(qptr);
  qreg[1] = ldg16(qptr + 32);

  float m_r[4], rinv[4];
#pragma unroll
  for (int i = 0; i < 4; ++i) {
    size_t idx = (size_t)(b * 20 + h) * 448 + tq0 + w * 16 + l4 * 4 + i;
    m_r[i]  = ML[idx * 2];
    rinv[i] = 1.f / ML[idx * 2 + 1];
  }
  float* wbase = Wout + ((size_t)(b * 3 + ha) * 448 + tq0) * 1500;

  const char* const Kc = (const char*)Kf +
      ((size_t)(b * 20 + h) * 192 << 10) + (lane << 4);

  bf16x8 bk[4][2];
#pragma unroll
  for (int ni = 0; ni < 4; ++ni)
#pragma unroll
    for (int h2 = 0; h2 < 2; ++h2)
      bk[ni][h2] = ldg16(Kc + ((ni * 2 + h2) << 10));

#pragma unroll 1
  for (int kt = 0; kt < 24; ++kt) {
    bf16x8 bkn[4][2];
    if (kt < 23) {
      const char* kp = Kc + (size_t)(kt + 1) * 8192;
#pragma unroll
      for (int ni = 0; ni < 4; ++ni)
#pragma unroll
        for (int h2 = 0; h2 < 2; ++h2)
          bkn[ni][h2] = ldg16(kp + ((ni * 2 + h2) << 10));
    }

    f32x4 s[4] = {};
    __builtin_amdgcn_s_setprio(1);
#pragma unroll
    for (int h2 = 0; h2 < 2; ++h2)
#pragma unroll
      for (int ni = 0; ni < 4; ++ni)
        s[ni] = __builtin_amdgcn_mfma_f32_16x16x32_bf16(qreg[h2], bk[ni][h2], s[ni], 0, 0, 0);
    __builtin_amdgcn_s_setprio(0);

    const int k0 = kt << 6;
#pragma unroll
    for (int ni = 0; ni < 4; ++ni) {
      const int col = k0 + ni * 16 + l15;
      if (col < 1500) {
#pragma unroll
        for (int i = 0; i < 4; ++i) {
          const int row = w * 16 + l4 * 4 + i;
          wbase[(size_t)row * 1500 + col] = __expf(s[ni][i] - m_r[i]) * rinv[i];
        }
      }
    }

#pragma unroll
    for (int ni = 0; ni < 4; ++ni)
#pragma unroll
      for (int h2 = 0; h2 < 2; ++h2)
        bk[ni][h2] = bkn[ni][h2];
  }
}

// ---------------------------------------------------------------------------
extern "C" void kernel_launch(void* const* d_in, const int* in_sizes, int n_in,
                              void* d_out, int out_size, void* d_ws, size_t ws_size,
                              hipStream_t stream) {
  const float* x  = (const float*)d_in[0];
  const float* k  = (const float*)d_in[1];
  const float* v  = (const float*)d_in[2];
  const float* Wq = (const float*)d_in[3];
  const float* bq = (const float*)d_in[4];
  const float* Wo = (const float*)d_in[5];
  const float* bo = (const float*)d_in[6];
  float* out  = (float*)d_out;
  float* wout = out + (size_t)8 * 448 * 1280;

  char* ws = (char*)d_ws;
  unsigned short* wqb   = (unsigned short*)(ws);              //  3,276,800
  unsigned short* wob   = (unsigned short*)(ws + 3276800);    //  3,276,800
  unsigned short* xb    = (unsigned short*)(ws + 6553600);    //  9,175,040
  unsigned short* qs    = (unsigned short*)(ws + 15728640);   //  9,175,040
  unsigned short* kfrag = (unsigned short*)(ws + 24903680);   // 31,457,280
  unsigned short* vfrag = (unsigned short*)(ws + 56360960);   // 31,457,280
  float* ml             = (float*)(ws + 87818240);            //    573,440
  unsigned short* ao    = xb;   // xb dead after gemm1; attn output aliases it

  prep_kernel<<<7680, 256, 0, stream>>>(x, Wq, Wo, k, v, wqb, kfrag, vfrag);

  gemm_bt<0><<<560, 256, 0, stream>>>(xb, wqb, bq, (void*)qs, 3584, 1280, 1280, 0.125f);

  attn_kernel<<<8 * 20 * 7, 256, 0, stream>>>(qs, kfrag, vfrag, ao, ml);

  gemm_bt<1><<<560, 256, 0, stream>>>(ao, wob, bo, (void*)out, 3584, 1280, 1280, 1.0f);

  weights_kernel<<<8 * 3 * 7, 256, 0, stream>>>(qs, kfrag, ml, wout);
}